// Round 3
// baseline (6574.657 us; speedup 1.0000x reference)
//
#include <hip/hip_runtime.h>

typedef unsigned short ushort_t;
typedef unsigned int uint32;
typedef unsigned long long uint64;
typedef __attribute__((ext_vector_type(8))) __bf16 bf16x8;
typedef __attribute__((ext_vector_type(4))) float f32x4;

#define BB 64
#define LL 1024
#define DD 64
#define HH 512
#define HSEQ_N (BB * LL * HH)
#define HN_OFF HSEQ_N
#define XH_OFF (HSEQ_N + BB * HH)

#define NGRP 4          // batch groups (16 rows each)
#define NBLK 8          // blocks per group (64 cols x 3 gates each)
// d_ws layout (all tag-carrying u64, zeroed each launch):
//   [1024, +262144) h exchange: [par][g][row 16][colpair 256] u64 {2xbf16|tag}
//   [263168, +65536) LN partials: [par][g][combo 32][row 16][2] u64 {f32|tag}
#define WS_HEX_OFF 1024
#define WS_PS_OFF (1024 + 2 * NGRP * 16 * 256 * 8)
#define WS_TOTAL (WS_PS_OFF + 2 * NGRP * 32 * 16 * 2 * 8)

__device__ __forceinline__ ushort_t f2bf(float f) {
  union { float f; uint32 i; } v; v.f = f;
  uint32 r = (v.i + 0x7fffu + ((v.i >> 16) & 1u)) >> 16;
  return (ushort_t)r;
}
__device__ __forceinline__ __bf16 u2b(ushort_t u) {
  union { ushort_t u; __bf16 b; } v; v.u = u; return v.b;
}
__device__ __forceinline__ bf16x8 cvt8(const float* p) {
  float4 a = *(const float4*)p;
  float4 b = *(const float4*)(p + 4);
  bf16x8 r;
  r[0] = u2b(f2bf(a.x)); r[1] = u2b(f2bf(a.y)); r[2] = u2b(f2bf(a.z)); r[3] = u2b(f2bf(a.w));
  r[4] = u2b(f2bf(b.x)); r[5] = u2b(f2bf(b.y)); r[6] = u2b(f2bf(b.z)); r[7] = u2b(f2bf(b.w));
  return r;
}
__device__ __forceinline__ float sigm(float x) { return 1.0f / (1.0f + __expf(-x)); }
__device__ __forceinline__ float tanh_f(float x) {
  x = fminf(20.f, fmaxf(-20.f, x));
  float e = __expf(2.0f * x);
  return (e - 1.0f) / (e + 1.0f);
}

// Point-coherent exchange: relaxed agent-scope 8B atomics. Each u64 carries
// its own validity tag, so no fences, no flags, no drain on the critical path.
__device__ __forceinline__ void st_u64_agent(uint64* p, uint64 v) {
  __hip_atomic_store(p, v, __ATOMIC_RELAXED, __HIP_MEMORY_SCOPE_AGENT);
}
__device__ __forceinline__ uint64 ld_u64_agent(const uint64* p) {
  return __hip_atomic_load((uint64*)p, __ATOMIC_RELAXED, __HIP_MEMORY_SCOPE_AGENT);
}

// 32 blocks = 4 batch-groups x 8 col-groups, 768 threads = 12 waves.
// Wave v: gate s=v>>2 (r,z,n), col-subtile T=v&3 (16 cols of the block's 64).
// Weights for the wave's 16 output rows live in 72 VGPRs for the whole kernel.
// Per-step sync: self-validating tagged u64 exchange (single IC traversal).
__global__ __launch_bounds__(768) void gru_kernel(
    const float* __restrict__ x, const float* __restrict__ h0,
    const float* __restrict__ Wih, const float* __restrict__ Whh,
    const float* __restrict__ bih, const float* __restrict__ bhh,
    const float* __restrict__ gamma, const float* __restrict__ beta,
    float* __restrict__ out, uint64* __restrict__ h_ex, uint64* __restrict__ ps_ex)
{
  __shared__ __align__(16) ushort_t Abuf[16 * 520];   // h_{t-1} bf16 (full 512 cols)
  __shared__ __align__(16) ushort_t xbuf[16 * 80];    // x_t bf16
  __shared__ float grz[8][16 * 17];                   // sigmoid(r/z) tiles [s*4+T]
  __shared__ float2 statb[16];                        // (mu, rstd) per batch row

  const int tid = threadIdx.x;
  const int v = tid >> 6, lane = tid & 63, lo = lane & 15, hi = lane >> 4;
  const int s = v >> 2, T = v & 3;
  const int g = blockIdx.x & 3, c = blockIdx.x >> 2;  // c in [0,8)
  const int b0 = g * 16;
  const int colj = c * 64 + T * 16 + lo;              // h-index this lane produces
  const int rowW = s * HH + colj;                      // W row (gate-major 3H layout)

  // ---- weights into registers (bf16 fragments) ----
  bf16x8 wB[16], wI[2];
  {
    const float* wr = Whh + (size_t)rowW * HH + hi * 8;
    #pragma unroll
    for (int ks = 0; ks < 16; ++ks) wB[ks] = cvt8(wr + ks * 32);
    const float* wir = Wih + (size_t)rowW * DD + hi * 8;
    #pragma unroll
    for (int ks = 0; ks < 2; ++ks) wI[ks] = cvt8(wir + ks * 32);
  }
  const float bsum = bih[rowW] + bhh[rowW];  // r/z combined bias
  const float bgh = bhh[rowW];               // n: hidden-side bias
  const float bgi = bih[rowW];               // n: input-side bias

  float hprev[4], gmv = 0.f, btv = 0.f;
  if (s == 2) {
    gmv = gamma[colj]; btv = beta[colj];
    #pragma unroll
    for (int i = 0; i < 4; ++i) hprev[i] = h0[(size_t)(b0 + hi * 4 + i) * HH + colj];
  }

  // ---- stage h0 -> Abuf, x(0) -> xbuf ----
  for (int i = tid; i < 16 * 512; i += 768) {
    int row = i >> 9, col = i & 511;
    Abuf[row * 520 + col] = f2bf(h0[(size_t)(b0 + row) * HH + col]);
  }
  for (int i = tid; i < 1024; i += 768) {
    int row = i >> 6, d = i & 63;
    xbuf[row * 80 + d] = f2bf(x[((size_t)(b0 + row) * LL + 0) * DD + d]);
  }
  __syncthreads();

  for (int t = 0; t < LL; ++t) {
    // prefetch x(t+1) into regs (waves 9..11 own the xbuf refill)
    float xr[6];
    if (v >= 9) {
      int t1 = (t + 1 < LL) ? (t + 1) : (LL - 1);
      int sid = tid - 576;
      #pragma unroll
      for (int k = 0; k < 6; ++k) {
        int i = sid + k * 192;
        if (i < 1024) xr[k] = x[((size_t)(b0 + (i >> 6)) * LL + t1) * DD + (i & 63)];
      }
    }

    // ---- MFMA phase: A from LDS, B from registers ----
    f32x4 a0, a1, agi;
    #pragma unroll
    for (int i = 0; i < 4; ++i) {
      a0[i] = (s < 2) ? bsum : bgh;
      a1[i] = 0.f;
      agi[i] = bgi;
    }
    #pragma unroll
    for (int ks = 0; ks < 2; ++ks) {
      bf16x8 av = *(const bf16x8*)&xbuf[lo * 80 + ks * 32 + hi * 8];
      if (s < 2) a0 = __builtin_amdgcn_mfma_f32_16x16x32_bf16(av, wI[ks], a0, 0, 0, 0);
      else       agi = __builtin_amdgcn_mfma_f32_16x16x32_bf16(av, wI[ks], agi, 0, 0, 0);
    }
    #pragma unroll
    for (int ks = 0; ks < 16; ++ks) {
      bf16x8 av = *(const bf16x8*)&Abuf[lo * 520 + ks * 32 + hi * 8];
      if (ks & 1) a1 = __builtin_amdgcn_mfma_f32_16x16x32_bf16(av, wB[ks], a1, 0, 0, 0);
      else        a0 = __builtin_amdgcn_mfma_f32_16x16x32_bf16(av, wB[ks], a0, 0, 0, 0);
    }
    f32x4 gacc;
    #pragma unroll
    for (int i = 0; i < 4; ++i) gacc[i] = a0[i] + a1[i];

    if (s < 2) {
      #pragma unroll
      for (int i = 0; i < 4; ++i) grz[s * 4 + T][(hi * 4 + i) * 17 + lo] = sigm(gacc[i]);
    }
    __syncthreads();  // C: r,z tiles visible; Abuf/xbuf reads of step t done

    const uint32 tag = (uint32)(t + 1);
    uint64* hx = h_ex + (size_t)((t & 1) * NGRP + g) * 4096;

    if (s < 2) {
      // ---- poll-stage full h_t into Abuf (self-validating tagged u64s) ----
      uint64 vals[8];
      #pragma unroll
      for (int k = 0; k < 8; ++k) vals[k] = ld_u64_agent(hx + tid + k * 512);
      while (true) {
        int bad = 0;
        #pragma unroll
        for (int k = 0; k < 8; ++k) bad |= ((uint32)vals[k] != tag);
        if (!bad) break;
        #pragma unroll
        for (int k = 0; k < 8; ++k)
          if ((uint32)vals[k] != tag) vals[k] = ld_u64_agent(hx + tid + k * 512);
      }
      #pragma unroll
      for (int k = 0; k < 8; ++k) {
        int idx = tid + k * 512;
        int row = idx >> 8, cb = idx & 255;
        *(uint32*)&Abuf[row * 520 + cb * 2] = (uint32)(vals[k] >> 32);
      }
    } else {
      float hn[4];
      #pragma unroll
      for (int i = 0; i < 4; ++i) {
        float r = grz[T][(hi * 4 + i) * 17 + lo];
        float z = grz[4 + T][(hi * 4 + i) * 17 + lo];
        float n = tanh_f(agi[i] + r * gacc[i]);
        hn[i] = z * (hprev[i] - n) + n;
      }
      // pack 2 adjacent cols (even/odd lane pair) + tag -> agent u64 store
      {
        uint32 pk[4];
        #pragma unroll
        for (int i = 0; i < 4; ++i) {
          uint32 m = (uint32)f2bf(hn[i]);
          uint32 o = (uint32)__shfl_xor((int)m, 1, 64);
          pk[i] = (lo & 1) ? ((o & 0xffffu) | (m << 16)) : (m | (o << 16));
        }
        int p = lo & 1;
        int cb = c * 32 + T * 8 + (lo >> 1);
        int r0 = hi * 4 + 2 * p;
        st_u64_agent(&hx[r0 * 256 + cb], ((uint64)pk[2 * p] << 32) | tag);
        st_u64_agent(&hx[(r0 + 1) * 256 + cb], ((uint64)pk[2 * p + 1] << 32) | tag);
      }
      // LN partials over this wave's 16 cols (tagged f32 u64s)
      uint64* pu = ps_ex + (size_t)((t & 1) * NGRP + g) * 1024;
      #pragma unroll
      for (int i = 0; i < 4; ++i) {
        float sv = hn[i], sq = hn[i] * hn[i];
        #pragma unroll
        for (int m = 1; m < 16; m <<= 1) {
          sv += __shfl_xor(sv, m, 64);
          sq += __shfl_xor(sq, m, 64);
        }
        if (lo == 0) {
          union { float f; uint32 u; } fv, fq; fv.f = sv; fq.f = sq;
          int e = ((c * 4 + T) * 16 + (hi * 4 + i)) * 2;
          st_u64_agent(&pu[e], ((uint64)fv.u << 32) | tag);
          st_u64_agent(&pu[e + 1], ((uint64)fq.u << 32) | tag);
        }
      }
      if (t == LL - 1) {
        #pragma unroll
        for (int i = 0; i < 4; ++i)
          out[(size_t)HN_OFF + (size_t)(b0 + hi * 4 + i) * HH + colj] = hn[i];
      }
      #pragma unroll
      for (int i = 0; i < 4; ++i) hprev[i] = hn[i];

      if (v >= 9) {
        // xbuf refill from prefetched regs
        int sid = tid - 576;
        #pragma unroll
        for (int k = 0; k < 6; ++k) {
          int i = sid + k * 192;
          if (i < 1024) xbuf[(i >> 6) * 80 + (i & 63)] = f2bf(xr[k]);
        }
      }
      if (v == 8) {
        // fold the 32 per-group LN partials (poll tagged u64s) -> statb
        int r = lane >> 2, q = lane & 3;
        const uint64* pb = ps_ex + (size_t)((t & 1) * NGRP + g) * 1024;
        uint64 va[8], vb[8];
        #pragma unroll
        for (int j = 0; j < 8; ++j) {
          int u = q * 8 + j;
          int e = (u * 16 + r) * 2;
          va[j] = ld_u64_agent(pb + e);
          vb[j] = ld_u64_agent(pb + e + 1);
        }
        while (true) {
          int bad = 0;
          #pragma unroll
          for (int j = 0; j < 8; ++j)
            bad |= ((uint32)va[j] != tag) | ((uint32)vb[j] != tag);
          if (!bad) break;
          #pragma unroll
          for (int j = 0; j < 8; ++j) {
            int u = q * 8 + j;
            int e = (u * 16 + r) * 2;
            if ((uint32)va[j] != tag) va[j] = ld_u64_agent(pb + e);
            if ((uint32)vb[j] != tag) vb[j] = ld_u64_agent(pb + e + 1);
          }
        }
        float sv = 0.f, sq = 0.f;
        #pragma unroll
        for (int j = 0; j < 8; ++j) {
          union { uint32 u; float f; } ua, ub;
          ua.u = (uint32)(va[j] >> 32); ub.u = (uint32)(vb[j] >> 32);
          sv += ua.f; sq += ub.f;
        }
        sv += __shfl_xor(sv, 1, 64); sq += __shfl_xor(sq, 1, 64);
        sv += __shfl_xor(sv, 2, 64); sq += __shfl_xor(sq, 2, 64);
        if (q == 0) {
          float mu = sv * (1.0f / 512.0f);
          float var = sq * (1.0f / 512.0f) - mu * mu;
          statb[r] = make_float2(mu, rsqrtf(var + 1e-5f));
        }
      }
    }
    __syncthreads();  // F: Abuf/xbuf/stats ready

    if (s == 2) {     // hseq(t) write overlaps next step's MFMA phase
      #pragma unroll
      for (int i = 0; i < 4; ++i) {
        float2 st = statb[hi * 4 + i];
        float y = (hprev[i] - st.x) * st.y * gmv + btv;
        out[((size_t)(b0 + hi * 4 + i) * LL + t) * HH + colj] = y;
      }
    }
  }
}

// x_hat = h_seq @ W_pred^T + b_pred, MFMA-based. Wave v owns output cols
// d = v*16 + lo (N=64 = 4 waves x 16). A-fragments straight from global
// (16 rows x 128B coalesced segments); W_pred in registers; fp32 accum.
__global__ __launch_bounds__(256) void pred_kernel(
    float* __restrict__ out, const float* __restrict__ Wp, const float* __restrict__ bp)
{
  const int tid = threadIdx.x;
  const int v = tid >> 6, lane = tid & 63, lo = lane & 15, hi = lane >> 4;
  const int d = v * 16 + lo;

  bf16x8 wP[16];
  const float* wr = Wp + (size_t)d * HH + hi * 8;
  #pragma unroll
  for (int ks = 0; ks < 16; ++ks) wP[ks] = cvt8(wr + ks * 32);
  const float bpf = bp[d];

  #pragma unroll
  for (int rt = 0; rt < 2; ++rt) {
    const size_t row0 = ((size_t)blockIdx.x * 2 + rt) * 16;
    const float* ap = out + (row0 + lo) * HH + hi * 8;
    f32x4 acc;
    #pragma unroll
    for (int i = 0; i < 4; ++i) acc[i] = 0.f;
    #pragma unroll
    for (int ks = 0; ks < 16; ++ks) {
      bf16x8 av = cvt8(ap + ks * 32);
      acc = __builtin_amdgcn_mfma_f32_16x16x32_bf16(av, wP[ks], acc, 0, 0, 0);
    }
    #pragma unroll
    for (int i = 0; i < 4; ++i)
      out[(size_t)XH_OFF + (row0 + hi * 4 + i) * DD + d] = acc[i] + bpf;
  }
}

extern "C" void kernel_launch(void* const* d_in, const int* in_sizes, int n_in,
                              void* d_out, int out_size, void* d_ws, size_t ws_size,
                              hipStream_t stream) {
  const float* x   = (const float*)d_in[0];
  const float* h0  = (const float*)d_in[1];
  const float* Wih = (const float*)d_in[2];
  const float* Whh = (const float*)d_in[3];
  const float* bih = (const float*)d_in[4];
  const float* bhh = (const float*)d_in[5];
  const float* gam = (const float*)d_in[6];
  const float* bet = (const float*)d_in[7];
  const float* Wp  = (const float*)d_in[8];
  const float* bp  = (const float*)d_in[9];
  float* out = (float*)d_out;

  uint64* h_ex = (uint64*)((char*)d_ws + WS_HEX_OFF);
  uint64* ps_ex = (uint64*)((char*)d_ws + WS_PS_OFF);

  // all tag words must start != any live tag (harness poisons d_ws with 0xAA)
  hipMemsetAsync(d_ws, 0, WS_TOTAL, stream);

  hipLaunchKernelGGL(gru_kernel, dim3(NGRP * NBLK), dim3(768), 0, stream,
                     x, h0, Wih, Whh, bih, bhh, gam, bet, out, h_ex, ps_ex);
  hipLaunchKernelGGL(pred_kernel, dim3(BB * LL / 32), dim3(256), 0, stream,
                     out, Wp, bp);
}

// Round 4
// 5851.612 us; speedup vs baseline: 1.1236x; 1.1236x over previous
//
#include <hip/hip_runtime.h>

typedef unsigned short ushort_t;
typedef unsigned int uint32;
typedef unsigned long long uint64;
typedef __attribute__((ext_vector_type(8))) __bf16 bf16x8;
typedef __attribute__((ext_vector_type(4))) float f32x4;

#define BB 64
#define LL 1024
#define DD 64
#define HH 512
#define HSEQ_N (BB * LL * HH)
#define HN_OFF HSEQ_N
#define XH_OFF (HSEQ_N + BB * HH)

#define NGRP 4          // batch groups (16 rows each)
#define NBLK 8          // blocks per group (64 cols x 3 gates each)
// d_ws layout:
//   [0, 1024) flags: group g at g*64 u32; 32 flags (c*4+T), one 128B line
//   [1024, +262144) h_ex u32: [par4][g][row 16][colpair 256] = 16KB per (par,g)
//   [263168, +65536) ps float2: [par4][g][combo 32][row 16]
#define WS_HEX_OFF 1024
#define WS_PS_OFF (1024 + 4 * NGRP * 4096 * 4)
#define WS_FLAG_BYTES 1024

__device__ __forceinline__ ushort_t f2bf(float f) {
  union { float f; uint32 i; } v; v.f = f;
  uint32 r = (v.i + 0x7fffu + ((v.i >> 16) & 1u)) >> 16;
  return (ushort_t)r;
}
__device__ __forceinline__ __bf16 u2b(ushort_t u) {
  union { ushort_t u; __bf16 b; } v; v.u = u; return v.b;
}
__device__ __forceinline__ bf16x8 cvt8(const float* p) {
  float4 a = *(const float4*)p;
  float4 b = *(const float4*)(p + 4);
  bf16x8 r;
  r[0] = u2b(f2bf(a.x)); r[1] = u2b(f2bf(a.y)); r[2] = u2b(f2bf(a.z)); r[3] = u2b(f2bf(a.w));
  r[4] = u2b(f2bf(b.x)); r[5] = u2b(f2bf(b.y)); r[6] = u2b(f2bf(b.z)); r[7] = u2b(f2bf(b.w));
  return r;
}
__device__ __forceinline__ float sigm(float x) { return 1.0f / (1.0f + __expf(-x)); }
__device__ __forceinline__ float tanh_f(float x) {
  x = fminf(20.f, fmaxf(-20.f, x));
  float e = __expf(2.0f * x);
  return (e - 1.0f) / (e + 1.0f);
}

// Point-coherent exchange: relaxed agent-scope atomics (write-through to the
// coherence point; cache-bypass loads). Data-before-flag ordering comes from
// the producer wave's own `s_waitcnt vmcnt(0)` before its flag store.
__device__ __forceinline__ void st_u32_agent(uint32* p, uint32 v) {
  __hip_atomic_store(p, v, __ATOMIC_RELAXED, __HIP_MEMORY_SCOPE_AGENT);
}
__device__ __forceinline__ void st_u64_agent(uint64* p, uint64 v) {
  __hip_atomic_store(p, v, __ATOMIC_RELAXED, __HIP_MEMORY_SCOPE_AGENT);
}
__device__ __forceinline__ uint32 ld_u32_agent(const uint32* p) {
  return __hip_atomic_load((uint32*)p, __ATOMIC_RELAXED, __HIP_MEMORY_SCOPE_AGENT);
}
__device__ __forceinline__ uint64 ld_u64_agent(const uint64* p) {
  return __hip_atomic_load((uint64*)p, __ATOMIC_RELAXED, __HIP_MEMORY_SCOPE_AGENT);
}

// 32 blocks = 4 batch-groups x 8 col-groups, 768 threads = 12 waves.
// Wave v: gate s=v>>2 (r,z,n), col-subtile T=v&3 (16 cols of the block's 64).
// Weights for the wave's 16 output rows live in 72 VGPRs for the whole kernel.
// Sync: per-PRODUCER-WAVE flags (32/group). Producer waves drain their own
// stores (per-wave vmcnt) and signal; consumer waves self-poll then reload.
// Only 2 block barriers per step (C: grz handoff, F: Abuf/xbuf/stats ready).
__global__ __launch_bounds__(768) void gru_kernel(
    const float* __restrict__ x, const float* __restrict__ h0,
    const float* __restrict__ Wih, const float* __restrict__ Whh,
    const float* __restrict__ bih, const float* __restrict__ bhh,
    const float* __restrict__ gamma, const float* __restrict__ beta,
    float* __restrict__ out, uint32* __restrict__ cnt,
    uint32* __restrict__ h_ex, float2* __restrict__ ps_ex)
{
  __shared__ __align__(16) ushort_t Abuf[16 * 520];   // h_{t-1} bf16 (full 512 cols)
  __shared__ __align__(16) ushort_t xbuf[16 * 80];    // x_t bf16
  __shared__ float grz[8][16 * 17];                   // sigmoid(r/z) tiles [s*4+T]
  __shared__ float2 statb[16];                        // (mu, rstd) per batch row

  const int tid = threadIdx.x;
  const int v = tid >> 6, lane = tid & 63, lo = lane & 15, hi = lane >> 4;
  const int s = v >> 2, T = v & 3;
  const int g = blockIdx.x & 3, c = blockIdx.x >> 2;  // c in [0,8)
  const int b0 = g * 16;
  const int colj = c * 64 + T * 16 + lo;              // h-index this lane produces
  const int rowW = s * HH + colj;                      // W row (gate-major 3H layout)

  // ---- weights into registers (bf16 fragments) ----
  bf16x8 wB[16], wI[2];
  {
    const float* wr = Whh + (size_t)rowW * HH + hi * 8;
    #pragma unroll
    for (int ks = 0; ks < 16; ++ks) wB[ks] = cvt8(wr + ks * 32);
    const float* wir = Wih + (size_t)rowW * DD + hi * 8;
    #pragma unroll
    for (int ks = 0; ks < 2; ++ks) wI[ks] = cvt8(wir + ks * 32);
  }
  const float bsum = bih[rowW] + bhh[rowW];  // r/z combined bias
  const float bgh = bhh[rowW];               // n: hidden-side bias
  const float bgi = bih[rowW];               // n: input-side bias

  float hprev[4], gmv = 0.f, btv = 0.f;
  if (s == 2) {
    gmv = gamma[colj]; btv = beta[colj];
    #pragma unroll
    for (int i = 0; i < 4; ++i) hprev[i] = h0[(size_t)(b0 + hi * 4 + i) * HH + colj];
  }

  // ---- stage h0 -> Abuf, x(0) -> xbuf ----
  for (int i = tid; i < 16 * 512; i += 768) {
    int row = i >> 9, col = i & 511;
    Abuf[row * 520 + col] = f2bf(h0[(size_t)(b0 + row) * HH + col]);
  }
  for (int i = tid; i < 1024; i += 768) {
    int row = i >> 6, d = i & 63;
    xbuf[row * 80 + d] = f2bf(x[((size_t)(b0 + row) * LL + 0) * DD + d]);
  }
  __syncthreads();

  uint32* fb = cnt + g * 64;   // 32 flags (u32), one 128B line per group

  for (int t = 0; t < LL; ++t) {
    // prefetch x(t+1) into regs (waves 9..11 own the xbuf refill)
    float xr[6];
    if (v >= 9) {
      int t1 = (t + 1 < LL) ? (t + 1) : (LL - 1);
      int sid = tid - 576;
      #pragma unroll
      for (int k = 0; k < 6; ++k) {
        int i = sid + k * 192;
        if (i < 1024) xr[k] = x[((size_t)(b0 + (i >> 6)) * LL + t1) * DD + (i & 63)];
      }
    }

    // ---- MFMA phase: A from LDS, B from registers ----
    f32x4 a0, a1, agi;
    #pragma unroll
    for (int i = 0; i < 4; ++i) {
      a0[i] = (s < 2) ? bsum : bgh;
      a1[i] = 0.f;
      agi[i] = bgi;
    }
    #pragma unroll
    for (int ks = 0; ks < 2; ++ks) {
      bf16x8 av = *(const bf16x8*)&xbuf[lo * 80 + ks * 32 + hi * 8];
      if (s < 2) a0 = __builtin_amdgcn_mfma_f32_16x16x32_bf16(av, wI[ks], a0, 0, 0, 0);
      else       agi = __builtin_amdgcn_mfma_f32_16x16x32_bf16(av, wI[ks], agi, 0, 0, 0);
    }
    #pragma unroll
    for (int ks = 0; ks < 16; ++ks) {
      bf16x8 av = *(const bf16x8*)&Abuf[lo * 520 + ks * 32 + hi * 8];
      if (ks & 1) a1 = __builtin_amdgcn_mfma_f32_16x16x32_bf16(av, wB[ks], a1, 0, 0, 0);
      else        a0 = __builtin_amdgcn_mfma_f32_16x16x32_bf16(av, wB[ks], a0, 0, 0, 0);
    }
    f32x4 gacc;
    #pragma unroll
    for (int i = 0; i < 4; ++i) gacc[i] = a0[i] + a1[i];

    if (s < 2) {
      #pragma unroll
      for (int i = 0; i < 4; ++i) grz[s * 4 + T][(hi * 4 + i) * 17 + lo] = sigm(gacc[i]);
    }
    __syncthreads();  // C: r,z tiles visible; all Abuf/xbuf reads of step t done

    const uint32 tag = (uint32)(t + 1);
    const int par = t & 3;

    if (s == 2) {
      // ================= PRODUCER WAVES (4) =================
      float hn[4];
      #pragma unroll
      for (int i = 0; i < 4; ++i) {
        float r = grz[T][(hi * 4 + i) * 17 + lo];
        float z = grz[4 + T][(hi * 4 + i) * 17 + lo];
        float n = tanh_f(agi[i] + r * gacc[i]);
        hn[i] = z * (hprev[i] - n) + n;
      }
      // pack 2 adjacent cols (even/odd lane pair) -> 2 agent u32 stores
      uint32* hx32 = h_ex + (size_t)(par * NGRP + g) * 4096;
      {
        uint32 pk[4];
        #pragma unroll
        for (int i = 0; i < 4; ++i) {
          uint32 m = (uint32)f2bf(hn[i]);
          uint32 o = (uint32)__shfl_xor((int)m, 1, 64);
          pk[i] = (lo & 1) ? ((o & 0xffffu) | (m << 16)) : (m | (o << 16));
        }
        int p = lo & 1;
        int cb = c * 32 + T * 8 + (lo >> 1);
        int r0 = hi * 4 + 2 * p;
        st_u32_agent(&hx32[r0 * 256 + cb], pk[2 * p]);
        st_u32_agent(&hx32[(r0 + 1) * 256 + cb], pk[2 * p + 1]);
      }
      // LN partials over this wave's 16 cols (float2 agent stores)
      float2* pp = ps_ex + (size_t)(par * NGRP + g) * 512 + (c * 4 + T) * 16;
      #pragma unroll
      for (int i = 0; i < 4; ++i) {
        float sv = hn[i], sq = hn[i] * hn[i];
        #pragma unroll
        for (int m = 1; m < 16; m <<= 1) {
          sv += __shfl_xor(sv, m, 64);
          sq += __shfl_xor(sq, m, 64);
        }
        if (lo == 0) {
          union { float2 f; uint64 u; } uu; uu.f = make_float2(sv, sq);
          st_u64_agent((uint64*)&pp[hi * 4 + i], uu.u);
        }
      }
      if (t == LL - 1) {
        #pragma unroll
        for (int i = 0; i < 4; ++i)
          out[(size_t)HN_OFF + (size_t)(b0 + hi * 4 + i) * HH + colj] = hn[i];
      }
      #pragma unroll
      for (int i = 0; i < 4; ++i) hprev[i] = hn[i];

      // drain THIS WAVE's stores to the coherence point, then signal own flag
      asm volatile("s_waitcnt vmcnt(0)" ::: "memory");
      __builtin_amdgcn_sched_barrier(0);
      if (lane == 0) st_u32_agent(&fb[c * 4 + T], tag);

      // side jobs while consumers reload
      if (v >= 9) {
        int sid = tid - 576;
        #pragma unroll
        for (int k = 0; k < 6; ++k) {
          int i = sid + k * 192;
          if (i < 1024) xbuf[(i >> 6) * 80 + (i & 63)] = f2bf(xr[k]);
        }
      }
      if (v == 8) {
        // wait for all 32 producer flags, then fold LN partials -> statb
        while (true) {
          uint32 f = (lane < 32) ? ld_u32_agent(&fb[lane]) : tag;
          if (__all((int)(f >= tag))) break;
          __builtin_amdgcn_s_sleep(1);
        }
        int r = lane >> 2, q = lane & 3;
        const uint64* pb = (const uint64*)(ps_ex + (size_t)(par * NGRP + g) * 512);
        float sv = 0.f, sq = 0.f;
        #pragma unroll
        for (int j = 0; j < 8; ++j) {
          int u = q * 8 + j;
          union { uint64 u64; float2 f; } uu;
          uu.u64 = ld_u64_agent(pb + u * 16 + r);
          sv += uu.f.x; sq += uu.f.y;
        }
        sv += __shfl_xor(sv, 1, 64); sq += __shfl_xor(sq, 1, 64);
        sv += __shfl_xor(sv, 2, 64); sq += __shfl_xor(sq, 2, 64);
        if (q == 0) {
          float mu = sv * (1.0f / 512.0f);
          float var = sq * (1.0f / 512.0f) - mu * mu;
          statb[r] = make_float2(mu, rsqrtf(var + 1e-5f));
        }
      }
    } else if (t + 1 < LL) {
      // ================= CONSUMER WAVES (8) =================
      // self-poll the 32 producer flags, then one-shot reload own Abuf slice
      while (true) {
        uint32 f = (lane < 32) ? ld_u32_agent(&fb[lane]) : tag;
        if (__all((int)(f >= tag))) break;
        __builtin_amdgcn_s_sleep(1);
      }
      const uint64* hx8 = (const uint64*)(h_ex + (size_t)(par * NGRP + g) * 4096);
      #pragma unroll
      for (int k = 0; k < 4; ++k) {
        int idx = v * 256 + k * 64 + lane;   // [0, 2048)
        uint64 vv = ld_u64_agent(hx8 + idx);
        int row = idx >> 7, c8 = idx & 127;
        *(uint64*)&Abuf[row * 520 + c8 * 4] = vv;
      }
    }
    __syncthreads();  // F: Abuf/xbuf/stats ready

    if (s == 2) {     // hseq(t) write overlaps next step's MFMA phase
      #pragma unroll
      for (int i = 0; i < 4; ++i) {
        float2 st = statb[hi * 4 + i];
        float y = (hprev[i] - st.x) * st.y * gmv + btv;
        out[((size_t)(b0 + hi * 4 + i) * LL + t) * HH + colj] = y;
      }
    }
  }
}

// x_hat = h_seq @ W_pred^T + b_pred, MFMA-based. Wave v owns output cols
// d = v*16 + lo (N=64 = 4 waves x 16). A-fragments straight from global
// (16 rows x 128B coalesced segments); W_pred in registers; fp32 accum.
__global__ __launch_bounds__(256) void pred_kernel(
    float* __restrict__ out, const float* __restrict__ Wp, const float* __restrict__ bp)
{
  const int tid = threadIdx.x;
  const int v = tid >> 6, lane = tid & 63, lo = lane & 15, hi = lane >> 4;
  const int d = v * 16 + lo;

  bf16x8 wP[16];
  const float* wr = Wp + (size_t)d * HH + hi * 8;
  #pragma unroll
  for (int ks = 0; ks < 16; ++ks) wP[ks] = cvt8(wr + ks * 32);
  const float bpf = bp[d];

  #pragma unroll
  for (int rt = 0; rt < 2; ++rt) {
    const size_t row0 = ((size_t)blockIdx.x * 2 + rt) * 16;
    const float* ap = out + (row0 + lo) * HH + hi * 8;
    f32x4 acc;
    #pragma unroll
    for (int i = 0; i < 4; ++i) acc[i] = 0.f;
    #pragma unroll
    for (int ks = 0; ks < 16; ++ks) {
      bf16x8 av = cvt8(ap + ks * 32);
      acc = __builtin_amdgcn_mfma_f32_16x16x32_bf16(av, wP[ks], acc, 0, 0, 0);
    }
    #pragma unroll
    for (int i = 0; i < 4; ++i)
      out[(size_t)XH_OFF + (row0 + hi * 4 + i) * DD + d] = acc[i] + bpf;
  }
}

extern "C" void kernel_launch(void* const* d_in, const int* in_sizes, int n_in,
                              void* d_out, int out_size, void* d_ws, size_t ws_size,
                              hipStream_t stream) {
  const float* x   = (const float*)d_in[0];
  const float* h0  = (const float*)d_in[1];
  const float* Wih = (const float*)d_in[2];
  const float* Whh = (const float*)d_in[3];
  const float* bih = (const float*)d_in[4];
  const float* bhh = (const float*)d_in[5];
  const float* gam = (const float*)d_in[6];
  const float* bet = (const float*)d_in[7];
  const float* Wp  = (const float*)d_in[8];
  const float* bp  = (const float*)d_in[9];
  float* out = (float*)d_out;

  uint32* cnt   = (uint32*)d_ws;
  uint32* h_ex  = (uint32*)((char*)d_ws + WS_HEX_OFF);
  float2* ps_ex = (float2*)((char*)d_ws + WS_PS_OFF);

  // flags must start at 0 (monotone tags 1..1024); harness poisons with 0xAA.
  // h_ex/ps_ex need no init: every read is flag-gated behind a tagged write.
  hipMemsetAsync(d_ws, 0, WS_FLAG_BYTES, stream);

  hipLaunchKernelGGL(gru_kernel, dim3(NGRP * NBLK), dim3(768), 0, stream,
                     x, h0, Wih, Whh, bih, bhh, gam, bet, out, cnt, h_ex, ps_ex);
  hipLaunchKernelGGL(pred_kernel, dim3(BB * LL / 32), dim3(256), 0, stream,
                     out, Wp, bp);
}

// Round 7
// 5547.066 us; speedup vs baseline: 1.1852x; 1.0549x over previous
//
#include <hip/hip_runtime.h>

typedef unsigned short ushort_t;
typedef unsigned int uint32;
typedef unsigned long long uint64;
typedef __attribute__((ext_vector_type(8))) __bf16 bf16x8;
typedef __attribute__((ext_vector_type(4))) float f32x4;

#define BB 64
#define LL 1024
#define DD 64
#define HH 512
#define HSEQ_N (BB * LL * HH)
#define HN_OFF HSEQ_N
#define XH_OFF (HSEQ_N + BB * HH)

#define NGRP 4          // batch groups (16 rows each)
#define NBLK 8          // blocks per group (64 cols x 3 gates each)
// d_ws layout:
//   [0, 1024)       sentinels: group g at g*256B, 8 words (c*8 u32, 32B apart)
//   [1024, +262144) h_ex u64: [par2][g][row 16][colpair 256] {2xbf16|tag}
//   [263168, +65536) ps u64:  [par2][g][combo 32][row 16][2]  {f32|tag}
#define WS_HEX_OFF 1024
#define WS_PS_OFF (1024 + 2 * NGRP * 4096 * 8)
#define WS_FLAG_BYTES 1024

__device__ __forceinline__ ushort_t f2bf(float f) {
  union { float f; uint32 i; } v; v.f = f;
  uint32 r = (v.i + 0x7fffu + ((v.i >> 16) & 1u)) >> 16;
  return (ushort_t)r;
}
__device__ __forceinline__ __bf16 u2b(ushort_t u) {
  union { ushort_t u; __bf16 b; } v; v.u = u; return v.b;
}
__device__ __forceinline__ bf16x8 cvt8(const float* p) {
  float4 a = *(const float4*)p;
  float4 b = *(const float4*)(p + 4);
  bf16x8 r;
  r[0] = u2b(f2bf(a.x)); r[1] = u2b(f2bf(a.y)); r[2] = u2b(f2bf(a.z)); r[3] = u2b(f2bf(a.w));
  r[4] = u2b(f2bf(b.x)); r[5] = u2b(f2bf(b.y)); r[6] = u2b(f2bf(b.z)); r[7] = u2b(f2bf(b.w));
  return r;
}
__device__ __forceinline__ float sigm(float x) { return 1.0f / (1.0f + __expf(-x)); }
__device__ __forceinline__ float tanh_f(float x) {
  x = fminf(20.f, fmaxf(-20.f, x));
  float e = __expf(2.0f * x);
  return (e - 1.0f) / (e + 1.0f);
}

// Point-coherent exchange: relaxed agent-scope atomics. Data u64s carry their
// own validity tag (self-validating; round-3-verified numerics). A per-block
// SENTINEL (advisory only) gates the consumers' bulk pass so the tagged
// retry never floods the fabric. No producer drain on the critical path: the
// producer's stores age through the sentinel/observe/bulk legs and the next
// __syncthreads drains them for free.
__device__ __forceinline__ void st_u32_agent(uint32* p, uint32 v) {
  __hip_atomic_store(p, v, __ATOMIC_RELAXED, __HIP_MEMORY_SCOPE_AGENT);
}
__device__ __forceinline__ void st_u64_agent(uint64* p, uint64 v) {
  __hip_atomic_store(p, v, __ATOMIC_RELAXED, __HIP_MEMORY_SCOPE_AGENT);
}
__device__ __forceinline__ uint32 ld_u32_agent(const uint32* p) {
  return __hip_atomic_load((uint32*)p, __ATOMIC_RELAXED, __HIP_MEMORY_SCOPE_AGENT);
}
__device__ __forceinline__ uint64 ld_u64_agent(const uint64* p) {
  return __hip_atomic_load((uint64*)p, __ATOMIC_RELAXED, __HIP_MEMORY_SCOPE_AGENT);
}
__device__ __forceinline__ void st_lds(uint32* p, uint32 v) {
  __hip_atomic_store(p, v, __ATOMIC_RELAXED, __HIP_MEMORY_SCOPE_WORKGROUP);
}
__device__ __forceinline__ uint32 ld_lds(const uint32* p) {
  return __hip_atomic_load((uint32*)p, __ATOMIC_RELAXED, __HIP_MEMORY_SCOPE_WORKGROUP);
}

// 32 blocks = 4 batch-groups x 8 col-groups, 768 threads = 12 waves.
// Wave v: gate s=v>>2 (r,z,n), col-subtile T=v&3 (16 cols of the block's 64).
// Weights for the wave's 16 output rows live in 72 VGPRs for the whole kernel.
// Per-step sync: tagged data + advisory sentinel + LDS token. Two
// __syncthreads per step (C: grz handoff, F: Abuf/xbuf/stats ready).
// All spins carry s_sleep backoff (hang-hardening, round 7).
__global__ __launch_bounds__(768) void gru_kernel(
    const float* __restrict__ x, const float* __restrict__ h0,
    const float* __restrict__ Wih, const float* __restrict__ Whh,
    const float* __restrict__ bih, const float* __restrict__ bhh,
    const float* __restrict__ gamma, const float* __restrict__ beta,
    float* __restrict__ out, uint32* __restrict__ cnt,
    uint64* __restrict__ h_ex, uint64* __restrict__ ps_ex)
{
  __shared__ __align__(16) ushort_t Abuf[16 * 520];   // h_{t-1} bf16 (full 512 cols)
  __shared__ __align__(16) ushort_t xbuf[16 * 80];    // x_t bf16
  __shared__ float grz[8][16 * 17];                   // sigmoid(r/z) tiles [s*4+T]
  __shared__ float2 statb[16];                        // (mu, rstd) per batch row
  __shared__ uint32 arr4[4];                          // producer-wave arrive tags
  __shared__ uint32 tok;                              // consumer go-token

  const int tid = threadIdx.x;
  const int v = tid >> 6, lane = tid & 63, lo = lane & 15, hi = lane >> 4;
  const int s = v >> 2, T = v & 3;
  const int g = blockIdx.x & 3, c = blockIdx.x >> 2;  // c in [0,8)
  const int b0 = g * 16;
  const int colj = c * 64 + T * 16 + lo;              // h-index this lane produces
  const int rowW = s * HH + colj;                      // W row (gate-major 3H layout)

  if (tid == 0) { arr4[0] = arr4[1] = arr4[2] = arr4[3] = 0; tok = 0; }

  // ---- weights into registers (bf16 fragments) ----
  bf16x8 wB[16], wI[2];
  {
    const float* wr = Whh + (size_t)rowW * HH + hi * 8;
    #pragma unroll
    for (int ks = 0; ks < 16; ++ks) wB[ks] = cvt8(wr + ks * 32);
    const float* wir = Wih + (size_t)rowW * DD + hi * 8;
    #pragma unroll
    for (int ks = 0; ks < 2; ++ks) wI[ks] = cvt8(wir + ks * 32);
  }
  const float bsum = bih[rowW] + bhh[rowW];  // r/z combined bias
  const float bgh = bhh[rowW];               // n: hidden-side bias
  const float bgi = bih[rowW];               // n: input-side bias

  float hprev[4], gmv = 0.f, btv = 0.f;
  if (s == 2) {
    gmv = gamma[colj]; btv = beta[colj];
    #pragma unroll
    for (int i = 0; i < 4; ++i) hprev[i] = h0[(size_t)(b0 + hi * 4 + i) * HH + colj];
  }

  // ---- stage h0 -> Abuf, x(0) -> xbuf ----
  for (int i = tid; i < 16 * 512; i += 768) {
    int row = i >> 9, col = i & 511;
    Abuf[row * 520 + col] = f2bf(h0[(size_t)(b0 + row) * HH + col]);
  }
  for (int i = tid; i < 1024; i += 768) {
    int row = i >> 6, d = i & 63;
    xbuf[row * 80 + d] = f2bf(x[((size_t)(b0 + row) * LL + 0) * DD + d]);
  }
  __syncthreads();

  uint32* fb = cnt + g * 64;   // 8 sentinels (u32, 32B apart) per group

  for (int t = 0; t < LL; ++t) {
    // prefetch x(t+1) into regs (waves 9..11 own the xbuf refill)
    float xr[6];
    if (v >= 9) {
      int t1 = (t + 1 < LL) ? (t + 1) : (LL - 1);
      int sid = tid - 576;
      #pragma unroll
      for (int k = 0; k < 6; ++k) {
        int i = sid + k * 192;
        if (i < 1024) xr[k] = x[((size_t)(b0 + (i >> 6)) * LL + t1) * DD + (i & 63)];
      }
    }

    // ---- MFMA phase: A from LDS, B from registers ----
    f32x4 a0, a1, agi;
    #pragma unroll
    for (int i = 0; i < 4; ++i) {
      a0[i] = (s < 2) ? bsum : bgh;
      a1[i] = 0.f;
      agi[i] = bgi;
    }
    #pragma unroll
    for (int ks = 0; ks < 2; ++ks) {
      bf16x8 av = *(const bf16x8*)&xbuf[lo * 80 + ks * 32 + hi * 8];
      if (s < 2) a0 = __builtin_amdgcn_mfma_f32_16x16x32_bf16(av, wI[ks], a0, 0, 0, 0);
      else       agi = __builtin_amdgcn_mfma_f32_16x16x32_bf16(av, wI[ks], agi, 0, 0, 0);
    }
    #pragma unroll
    for (int ks = 0; ks < 16; ++ks) {
      bf16x8 av = *(const bf16x8*)&Abuf[lo * 520 + ks * 32 + hi * 8];
      if (ks & 1) a1 = __builtin_amdgcn_mfma_f32_16x16x32_bf16(av, wB[ks], a1, 0, 0, 0);
      else        a0 = __builtin_amdgcn_mfma_f32_16x16x32_bf16(av, wB[ks], a0, 0, 0, 0);
    }
    f32x4 gacc;
    #pragma unroll
    for (int i = 0; i < 4; ++i) gacc[i] = a0[i] + a1[i];

    if (s < 2) {
      #pragma unroll
      for (int i = 0; i < 4; ++i) grz[s * 4 + T][(hi * 4 + i) * 17 + lo] = sigm(gacc[i]);
    }
    __syncthreads();  // C: r,z tiles visible; Abuf/xbuf reads of step t done

    const uint32 tag = (uint32)(t + 1);
    uint64* hx = h_ex + (size_t)((t & 1) * NGRP + g) * 4096;

    if (s == 2) {
      // ================= PRODUCER WAVES (8..11) =================
      float hn[4];
      #pragma unroll
      for (int i = 0; i < 4; ++i) {
        float r = grz[T][(hi * 4 + i) * 17 + lo];
        float z = grz[4 + T][(hi * 4 + i) * 17 + lo];
        float n = tanh_f(agi[i] + r * gacc[i]);
        hn[i] = z * (hprev[i] - n) + n;
      }
      // pack 2 adjacent cols (even/odd lane pair) + tag -> agent u64 stores
      {
        uint32 pk[4];
        #pragma unroll
        for (int i = 0; i < 4; ++i) {
          uint32 m = (uint32)f2bf(hn[i]);
          uint32 o = (uint32)__shfl_xor((int)m, 1, 64);
          pk[i] = (lo & 1) ? ((o & 0xffffu) | (m << 16)) : (m | (o << 16));
        }
        int p = lo & 1;
        int cb = c * 32 + T * 8 + (lo >> 1);
        int r0 = hi * 4 + 2 * p;
        st_u64_agent(&hx[r0 * 256 + cb], ((uint64)pk[2 * p] << 32) | tag);
        st_u64_agent(&hx[(r0 + 1) * 256 + cb], ((uint64)pk[2 * p + 1] << 32) | tag);
      }
      // LN partials over this wave's 16 cols (tagged f32 u64s)
      uint64* pu = ps_ex + (size_t)((t & 1) * NGRP + g) * 1024;
      #pragma unroll
      for (int i = 0; i < 4; ++i) {
        float sv = hn[i], sq = hn[i] * hn[i];
        #pragma unroll
        for (int m = 1; m < 16; m <<= 1) {
          sv += __shfl_xor(sv, m, 64);
          sq += __shfl_xor(sq, m, 64);
        }
        if (lo == 0) {
          union { float f; uint32 u; } fv, fq; fv.f = sv; fq.f = sq;
          int e = ((c * 4 + T) * 16 + (hi * 4 + i)) * 2;
          st_u64_agent(&pu[e], ((uint64)fv.u << 32) | tag);
          st_u64_agent(&pu[e + 1], ((uint64)fq.u << 32) | tag);
        }
      }
      if (t == LL - 1) {
        #pragma unroll
        for (int i = 0; i < 4; ++i)
          out[(size_t)HN_OFF + (size_t)(b0 + hi * 4 + i) * HH + colj] = hn[i];
      }
      #pragma unroll
      for (int i = 0; i < 4; ++i) hprev[i] = hn[i];

      // ---- sentinel: all 4 producer waves have ISSUED their stores ----
      __builtin_amdgcn_sched_barrier(0);   // keep arr-write after store issue
      if (lane == 0) st_lds(&arr4[T], tag);
      if (T == 3 && lane == 0) {
        while (ld_lds(&arr4[0]) < tag || ld_lds(&arr4[1]) < tag ||
               ld_lds(&arr4[2]) < tag)
          __builtin_amdgcn_s_sleep(1);
        st_u32_agent(&fb[c * 8], tag);     // advisory sentinel (no drain!)
      }

      // side jobs while consumers reload
      if (v >= 9) {
        int sid = tid - 576;
        #pragma unroll
        for (int k = 0; k < 6; ++k) {
          int i = sid + k * 192;
          if (i < 1024) xbuf[(i >> 6) * 80 + (i & 63)] = f2bf(xr[k]);
        }
      }
      if (v == 8) {
        // fold the 32 per-group LN partials (tagged retry) -> statb
        int r = lane >> 2, q = lane & 3;
        const uint64* pb = ps_ex + (size_t)((t & 1) * NGRP + g) * 1024;
        uint64 va[8], vb[8];
        #pragma unroll
        for (int j = 0; j < 8; ++j) {
          int e = ((q * 8 + j) * 16 + r) * 2;
          va[j] = ld_u64_agent(pb + e);
          vb[j] = ld_u64_agent(pb + e + 1);
        }
        int rounds = 0;
        while (true) {
          int bad = 0;
          #pragma unroll
          for (int j = 0; j < 8; ++j)
            bad |= ((uint32)va[j] != tag) | ((uint32)vb[j] != tag);
          if (!bad) break;
          if (++rounds >= 2) __builtin_amdgcn_s_sleep(1);
          #pragma unroll
          for (int j = 0; j < 8; ++j) {
            int e = ((q * 8 + j) * 16 + r) * 2;
            if ((uint32)va[j] != tag) va[j] = ld_u64_agent(pb + e);
            if ((uint32)vb[j] != tag) vb[j] = ld_u64_agent(pb + e + 1);
          }
        }
        float sv = 0.f, sq = 0.f;
        #pragma unroll
        for (int j = 0; j < 8; ++j) {
          union { uint32 u; float f; } ua, ub;
          ua.u = (uint32)(va[j] >> 32); ub.u = (uint32)(vb[j] >> 32);
          sv += ua.f; sq += ub.f;
        }
        sv += __shfl_xor(sv, 1, 64); sq += __shfl_xor(sq, 1, 64);
        sv += __shfl_xor(sv, 2, 64); sq += __shfl_xor(sq, 2, 64);
        if (q == 0) {
          float mu = sv * (1.0f / 512.0f);
          float var = sq * (1.0f / 512.0f) - mu * mu;
          statb[r] = make_float2(mu, rsqrtf(var + 1e-5f));
        }
      }
    } else if (t + 1 < LL) {
      // ================= CONSUMER WAVES (0..7) =================
      if (v == 0) {
        // observe all 8 block sentinels, then post the LDS go-token
        while (true) {
          uint32 f = (lane < 8) ? ld_u32_agent(&fb[lane * 8]) : tag;
          if (__all((int)(f >= tag))) break;
          __builtin_amdgcn_s_sleep(1);
        }
        if (lane == 0) st_lds(&tok, tag);
      } else {
        while (ld_lds(&tok) < tag) __builtin_amdgcn_s_sleep(1);
      }
      // bulk tagged reload of full h_t (gated -> rarely any retry)
      uint64 vals[8];
      #pragma unroll
      for (int k = 0; k < 8; ++k) vals[k] = ld_u64_agent(hx + tid + k * 512);
      int rounds = 0;
      while (true) {
        int bad = 0;
        #pragma unroll
        for (int k = 0; k < 8; ++k) bad |= ((uint32)vals[k] != tag);
        if (!bad) break;
        if (++rounds >= 2) __builtin_amdgcn_s_sleep(1);
        #pragma unroll
        for (int k = 0; k < 8; ++k)
          if ((uint32)vals[k] != tag) vals[k] = ld_u64_agent(hx + tid + k * 512);
      }
      #pragma unroll
      for (int k = 0; k < 8; ++k) {
        int idx = tid + k * 512;
        int row = idx >> 8, cb = idx & 255;
        *(uint32*)&Abuf[row * 520 + cb * 2] = (uint32)(vals[k] >> 32);
      }
    }
    __syncthreads();  // F: Abuf/xbuf/stats ready; producer stores aged -> free

    if (s == 2) {     // hseq(t) write overlaps next step's MFMA phase
      #pragma unroll
      for (int i = 0; i < 4; ++i) {
        float2 st = statb[hi * 4 + i];
        float y = (hprev[i] - st.x) * st.y * gmv + btv;
        out[((size_t)(b0 + hi * 4 + i) * LL + t) * HH + colj] = y;
      }
    }
  }
}

// x_hat = h_seq @ W_pred^T + b_pred, MFMA-based. Wave v owns output cols
// d = v*16 + lo (N=64 = 4 waves x 16). A-fragments straight from global
// (16 rows x 128B coalesced segments); W_pred in registers; fp32 accum.
__global__ __launch_bounds__(256) void pred_kernel(
    float* __restrict__ out, const float* __restrict__ Wp, const float* __restrict__ bp)
{
  const int tid = threadIdx.x;
  const int v = tid >> 6, lane = tid & 63, lo = lane & 15, hi = lane >> 4;
  const int d = v * 16 + lo;

  bf16x8 wP[16];
  const float* wr = Wp + (size_t)d * HH + hi * 8;
  #pragma unroll
  for (int ks = 0; ks < 16; ++ks) wP[ks] = cvt8(wr + ks * 32);
  const float bpf = bp[d];

  #pragma unroll
  for (int rt = 0; rt < 2; ++rt) {
    const size_t row0 = ((size_t)blockIdx.x * 2 + rt) * 16;
    const float* ap = out + (row0 + lo) * HH + hi * 8;
    f32x4 acc;
    #pragma unroll
    for (int i = 0; i < 4; ++i) acc[i] = 0.f;
    #pragma unroll
    for (int ks = 0; ks < 16; ++ks) {
      bf16x8 av = cvt8(ap + ks * 32);
      acc = __builtin_amdgcn_mfma_f32_16x16x32_bf16(av, wP[ks], acc, 0, 0, 0);
    }
    #pragma unroll
    for (int i = 0; i < 4; ++i)
      out[(size_t)XH_OFF + (row0 + hi * 4 + i) * DD + d] = acc[i] + bpf;
  }
}

extern "C" void kernel_launch(void* const* d_in, const int* in_sizes, int n_in,
                              void* d_out, int out_size, void* d_ws, size_t ws_size,
                              hipStream_t stream) {
  const float* x   = (const float*)d_in[0];
  const float* h0  = (const float*)d_in[1];
  const float* Wih = (const float*)d_in[2];
  const float* Whh = (const float*)d_in[3];
  const float* bih = (const float*)d_in[4];
  const float* bhh = (const float*)d_in[5];
  const float* gam = (const float*)d_in[6];
  const float* bet = (const float*)d_in[7];
  const float* Wp  = (const float*)d_in[8];
  const float* bp  = (const float*)d_in[9];
  float* out = (float*)d_out;

  uint32* cnt   = (uint32*)d_ws;
  uint64* h_ex  = (uint64*)((char*)d_ws + WS_HEX_OFF);
  uint64* ps_ex = (uint64*)((char*)d_ws + WS_PS_OFF);

  // sentinels must start 0 (monotone tags 1..1024); harness poisons with 0xAA.
  // h_ex/ps_ex need no init: every word is tag-validated (0xAAAAAAAA != any tag).
  hipMemsetAsync(d_ws, 0, WS_FLAG_BYTES, stream);

  hipLaunchKernelGGL(gru_kernel, dim3(NGRP * NBLK), dim3(768), 0, stream,
                     x, h0, Wih, Whh, bih, bhh, gam, bet, out, cnt, h_ex, ps_ex);
  hipLaunchKernelGGL(pred_kernel, dim3(BB * LL / 32), dim3(256), 0, stream,
                     out, Wp, bp);
}